// Round 2
// baseline (169.604 us; speedup 1.0000x reference)
//
#include <hip/hip_runtime.h>
#include <hip/hip_bf16.h>

// B=32, S=20 -> 640 graphs; N=128 nodes, F=64, HEADS=4, D=64.
#define ADJ_TH 0.05f

typedef __bf16 bf16x8 __attribute__((ext_vector_type(8)));
typedef __bf16 bf16x4 __attribute__((ext_vector_type(4)));
typedef float  f32x4  __attribute__((ext_vector_type(4)));

// ---- pre-kernel 1: W [64][256] f32 -> Wt [256][64] bf16 ----
__global__ void wt_convert_kernel(const float* __restrict__ W, __bf16* __restrict__ Wt) {
    int id = blockIdx.x * 256 + threadIdx.x;
    int o = id >> 6, k = id & 63;
    Wt[o * 64 + k] = (__bf16)W[k * 256 + o];
}

// ---- pre-kernel 2: adjacency -> bitmasks [bs][128 rows][4 words] ----
__global__ __launch_bounds__(256)
void mask_build_kernel(const float* __restrict__ adj, unsigned* __restrict__ mws) {
    int bs = blockIdx.x, tid = threadIdx.x;
    const float* ab = adj + (size_t)bs * 128 * 128;
    #pragma unroll
    for (int rp = 0; rp < 2; ++rp) {
        int widx = tid + rp * 256;          // 0..511
        int i = widx >> 2, wq = widx & 3;
        const float4* ap = reinterpret_cast<const float4*>(ab + i * 128 + wq * 32);
        unsigned bits = 0u;
        #pragma unroll
        for (int v = 0; v < 8; ++v) {
            float4 f = ap[v];
            bits |= (f.x < ADJ_TH ? 1u : 0u) << (4 * v + 0);
            bits |= (f.y < ADJ_TH ? 1u : 0u) << (4 * v + 1);
            bits |= (f.z < ADJ_TH ? 1u : 0u) << (4 * v + 2);
            bits |= (f.w < ADJ_TH ? 1u : 0u) << (4 * v + 3);
        }
        mws[(bs * 128 + i) * 4 + wq] = bits;
    }
}

// Swizzled index into ht_t [128 rows (o_local)][128 cols (node i)] bf16.
__device__ __forceinline__ int sw_idx(int o, int i) {
    return o * 128 + ((((i >> 3) ^ o) & 15) << 3) + (i & 7);
}

template<bool WSMASK>
__global__ __launch_bounds__(256, 4)
void gat_main_kernel(const float* __restrict__ hg, const float* __restrict__ adj,
                     const float* __restrict__ ag, const __bf16* __restrict__ Wt,
                     const unsigned* __restrict__ mws, float* __restrict__ out)
{
    const int bs  = blockIdx.x;
    const int tid = threadIdx.x;
    const int w   = tid >> 6;
    const int l   = tid & 63;
    const int l15 = l & 15;
    const int l4  = l >> 4;

    __shared__ __bf16   ht_t[128 * 128];              // 32 KB (2 heads per pass)
    __shared__ float    src_sh[2][128], tgt_sh[2][128]; // 2 KB
    __shared__ unsigned mask_sh[WSMASK ? 4 : 512];

    const float* hb = hg + (size_t)bs * 128 * 64;

    // mask bits -> registers (WSMASK) or LDS (fallback)
    uint4 mq[2];
    if constexpr (WSMASK) {
        #pragma unroll
        for (int m2 = 0; m2 < 2; ++m2) {
            int irow = 16 * (2 * w + m2) + l15;
            mq[m2] = *reinterpret_cast<const uint4*>(mws + ((size_t)bs * 128 + irow) * 4);
        }
    } else {
        const float* ab = adj + (size_t)bs * 128 * 128;
        #pragma unroll
        for (int rp = 0; rp < 2; ++rp) {
            int widx = tid + rp * 256;
            int i = widx >> 2, wq = widx & 3;
            const float4* ap = reinterpret_cast<const float4*>(ab + i * 128 + wq * 32);
            unsigned bits = 0u;
            #pragma unroll
            for (int v = 0; v < 8; ++v) {
                float4 f = ap[v];
                bits |= (f.x < ADJ_TH ? 1u : 0u) << (4 * v + 0);
                bits |= (f.y < ADJ_TH ? 1u : 0u) << (4 * v + 1);
                bits |= (f.z < ADJ_TH ? 1u : 0u) << (4 * v + 2);
                bits |= (f.w < ADJ_TH ? 1u : 0u) << (4 * v + 3);
            }
            mask_sh[i * 4 + wq] = bits;
        }
    }

    f32x4 acc2[2][4];                   // GEMM2 accumulators, persist across passes
    #pragma unroll
    for (int m2 = 0; m2 < 2; ++m2)
        #pragma unroll
        for (int nt = 0; nt < 4; ++nt) { f32x4 z = {0.f,0.f,0.f,0.f}; acc2[m2][nt] = z; }

    #pragma unroll 1
    for (int p = 0; p < 2; ++p) {       // pass = head pair {2p, 2p+1}
        // ---- A fragments of h (reloaded per pass; L2-hot on pass 1) ----
        bf16x8 af[2][2];
        #pragma unroll
        for (int m2 = 0; m2 < 2; ++m2) {
            int row = 16 * (2 * w + m2) + l15;
            #pragma unroll
            for (int ks = 0; ks < 2; ++ks) {
                const float4* p4 = reinterpret_cast<const float4*>(hb + row * 64 + 8 * l4 + 32 * ks);
                float4 lo = p4[0], hi = p4[1];
                bf16x8 v;
                v[0]=(__bf16)lo.x; v[1]=(__bf16)lo.y; v[2]=(__bf16)lo.z; v[3]=(__bf16)lo.w;
                v[4]=(__bf16)hi.x; v[5]=(__bf16)hi.y; v[6]=(__bf16)hi.z; v[7]=(__bf16)hi.w;
                af[m2][ks] = v;
            }
        }

        // ---- GEMM1 for this pass's 128 output channels + fused src/tgt ----
        #pragma unroll
        for (int hg2 = 0; hg2 < 2; ++hg2) {        // head-group within pass
            int h = 2 * p + hg2;
            float ps[2][4], pt[2][4];
            #pragma unroll
            for (int m2 = 0; m2 < 2; ++m2)
                #pragma unroll
                for (int r = 0; r < 4; ++r) { ps[m2][r] = 0.f; pt[m2][r] = 0.f; }

            #pragma unroll
            for (int nq = 0; nq < 4; ++nq) {
                int nt   = 4 * hg2 + nq;
                int oloc = 16 * nt + l15;          // 0..127
                int og   = 128 * p + oloc;         // global channel
                int d    = 16 * nq + l15;          // channel within head
                float a_s = ag[h * 128 + d];
                float a_t = ag[h * 128 + 64 + d];
                bf16x8 b0 = *reinterpret_cast<const bf16x8*>(Wt + og * 64 + 8 * l4);
                bf16x8 b1 = *reinterpret_cast<const bf16x8*>(Wt + og * 64 + 8 * l4 + 32);
                #pragma unroll
                for (int m2 = 0; m2 < 2; ++m2) {
                    f32x4 acc = {0.f,0.f,0.f,0.f};
                    acc = __builtin_amdgcn_mfma_f32_16x16x32_bf16(af[m2][0], b0, acc, 0,0,0);
                    acc = __builtin_amdgcn_mfma_f32_16x16x32_bf16(af[m2][1], b1, acc, 0,0,0);
                    int i0 = 16 * (2 * w + m2) + 4 * l4;
                    bf16x4 st;
                    st[0]=(__bf16)acc[0]; st[1]=(__bf16)acc[1];
                    st[2]=(__bf16)acc[2]; st[3]=(__bf16)acc[3];
                    *reinterpret_cast<bf16x4*>(&ht_t[sw_idx(oloc, i0)]) = st;
                    #pragma unroll
                    for (int r = 0; r < 4; ++r) {
                        ps[m2][r] += acc[r] * a_s;
                        pt[m2][r] += acc[r] * a_t;
                    }
                }
            }
            // reduce partial src/tgt over the 16 l15 lanes (o-dimension)
            #pragma unroll
            for (int s = 1; s < 16; s <<= 1)
                #pragma unroll
                for (int m2 = 0; m2 < 2; ++m2)
                    #pragma unroll
                    for (int r = 0; r < 4; ++r) {
                        ps[m2][r] += __shfl_xor(ps[m2][r], s);
                        pt[m2][r] += __shfl_xor(pt[m2][r], s);
                    }
            if (l15 == 0) {
                #pragma unroll
                for (int m2 = 0; m2 < 2; ++m2)
                    #pragma unroll
                    for (int r = 0; r < 4; ++r) {
                        int i = 16 * (2 * w + m2) + 4 * l4 + r;
                        src_sh[hg2][i] = ps[m2][r];
                        tgt_sh[hg2][i] = pt[m2][r];
                    }
            }
        }
        __syncthreads();

        // ---- phase 2: masked sigmoid-softmax + GEMM2 for heads 2p, 2p+1 ----
        #pragma unroll 1
        for (int hp = 0; hp < 2; ++hp) {
            bf16x8 bfr[4][4];
            #pragma unroll
            for (int nt = 0; nt < 4; ++nt)
                #pragma unroll
                for (int ks = 0; ks < 4; ++ks)
                    bfr[nt][ks] = *reinterpret_cast<const bf16x8*>(
                        &ht_t[sw_idx(64 * hp + 16 * nt + l15, 8 * l4 + 32 * ks)]);

            float tg[4][8];
            #pragma unroll
            for (int ks = 0; ks < 4; ++ks) {
                const float4* tp = reinterpret_cast<const float4*>(&tgt_sh[hp][8 * l4 + 32 * ks]);
                float4 t0 = tp[0], t1 = tp[1];
                tg[ks][0]=t0.x; tg[ks][1]=t0.y; tg[ks][2]=t0.z; tg[ks][3]=t0.w;
                tg[ks][4]=t1.x; tg[ks][5]=t1.y; tg[ks][6]=t1.z; tg[ks][7]=t1.w;
            }

            #pragma unroll
            for (int m2 = 0; m2 < 2; ++m2) {
                int irow = 16 * (2 * w + m2) + l15;
                float si = src_sh[hp][irow];
                unsigned mw[4];
                if constexpr (WSMASK) {
                    mw[0]=mq[m2].x; mw[1]=mq[m2].y; mw[2]=mq[m2].z; mw[3]=mq[m2].w;
                } else {
                    uint4 t = *reinterpret_cast<const uint4*>(&mask_sh[irow * 4]);
                    mw[0]=t.x; mw[1]=t.y; mw[2]=t.z; mw[3]=t.w;
                }

                float pf[4][8];
                float dloc = 0.f;
                #pragma unroll
                for (int ks = 0; ks < 4; ++ks)
                    #pragma unroll
                    for (int e = 0; e < 8; ++e) {
                        float x  = si + tg[ks][e];
                        float sg = __builtin_amdgcn_rcpf(1.0f + __expf(-x));
                        float pe = __expf(sg);
                        float pv = ((mw[ks] >> (8 * l4 + e)) & 1u) ? 0.f : pe;
                        pf[ks][e] = pv;
                        dloc += pv;
                    }
                dloc += __shfl_xor(dloc, 16);
                dloc += __shfl_xor(dloc, 32);
                float scale = 0.25f * __builtin_amdgcn_rcpf(fmaxf(dloc, 1e-20f));

                bf16x8 pa[4];
                #pragma unroll
                for (int ks = 0; ks < 4; ++ks) {
                    bf16x8 v;
                    #pragma unroll
                    for (int e = 0; e < 8; ++e) v[e] = (__bf16)(pf[ks][e] * scale);
                    pa[ks] = v;
                }
                #pragma unroll
                for (int nt = 0; nt < 4; ++nt) {
                    f32x4 acc = acc2[m2][nt];
                    #pragma unroll
                    for (int ks = 0; ks < 4; ++ks)
                        acc = __builtin_amdgcn_mfma_f32_16x16x32_bf16(pa[ks], bfr[nt][ks], acc, 0,0,0);
                    acc2[m2][nt] = acc;
                }
            }
        }
        __syncthreads();   // ht_t reused next pass
    }

    // ---- epilogue ----
    float* ob = out + (size_t)bs * 128 * 64;
    #pragma unroll
    for (int m2 = 0; m2 < 2; ++m2)
        #pragma unroll
        for (int nt = 0; nt < 4; ++nt)
            #pragma unroll
            for (int r = 0; r < 4; ++r)
                ob[(32 * w + 16 * m2 + 4 * l4 + r) * 64 + 16 * nt + l15] = acc2[m2][nt][r];
}

extern "C" void kernel_launch(void* const* d_in, const int* in_sizes, int n_in,
                              void* d_out, int out_size, void* d_ws, size_t ws_size,
                              hipStream_t stream) {
    const float* h   = (const float*)d_in[0];
    const float* adj = (const float*)d_in[1];
    const float* W   = (const float*)d_in[2];
    const float* a   = (const float*)d_in[3];
    float* out = (float*)d_out;

    __bf16*   Wt  = (__bf16*)d_ws;                              // 32 KB
    unsigned* mws = (unsigned*)((char*)d_ws + 65536);           // 1.25 MB
    const size_t need = 65536 + (size_t)640 * 128 * 4 * sizeof(unsigned);

    wt_convert_kernel<<<64, 256, 0, stream>>>(W, Wt);
    if (ws_size >= need) {
        mask_build_kernel<<<640, 256, 0, stream>>>(adj, mws);
        gat_main_kernel<true><<<640, 256, 0, stream>>>(h, adj, a, Wt, mws, out);
    } else {
        gat_main_kernel<false><<<640, 256, 0, stream>>>(h, adj, a, Wt, mws, out);
    }
}

// Round 3
// 140.850 us; speedup vs baseline: 1.2041x; 1.2041x over previous
//
#include <hip/hip_runtime.h>
#include <hip/hip_bf16.h>

// B=32, S=20 -> 640 graphs; N=128 nodes, F=64, HEADS=4, D=64.
#define ADJ_TH 0.05f

typedef __bf16 bf16x8 __attribute__((ext_vector_type(8)));
typedef __bf16 bf16x4 __attribute__((ext_vector_type(4)));
typedef float  f32x4  __attribute__((ext_vector_type(4)));

// ---- pre-kernel 1: W [64][256] f32 -> Wt [256][64] bf16 ----
__global__ void wt_convert_kernel(const float* __restrict__ W, __bf16* __restrict__ Wt) {
    int id = blockIdx.x * 256 + threadIdx.x;
    int o = id >> 6, k = id & 63;
    Wt[o * 64 + k] = (__bf16)W[k * 256 + o];
}

// ---- pre-kernel 2: adjacency -> bitmasks [bs][128 rows][4 words] ----
__global__ __launch_bounds__(256)
void mask_build_kernel(const float* __restrict__ adj, unsigned* __restrict__ mws) {
    int bs = blockIdx.x, tid = threadIdx.x;
    const float* ab = adj + (size_t)bs * 128 * 128;
    #pragma unroll
    for (int rp = 0; rp < 2; ++rp) {
        int widx = tid + rp * 256;          // 0..511
        int i = widx >> 2, wq = widx & 3;
        const float4* ap = reinterpret_cast<const float4*>(ab + i * 128 + wq * 32);
        unsigned bits = 0u;
        #pragma unroll
        for (int v = 0; v < 8; ++v) {
            float4 f = ap[v];
            bits |= (f.x < ADJ_TH ? 1u : 0u) << (4 * v + 0);
            bits |= (f.y < ADJ_TH ? 1u : 0u) << (4 * v + 1);
            bits |= (f.z < ADJ_TH ? 1u : 0u) << (4 * v + 2);
            bits |= (f.w < ADJ_TH ? 1u : 0u) << (4 * v + 3);
        }
        mws[(bs * 128 + i) * 4 + wq] = bits;
    }
}

// Swizzled index into ht_t [128 rows (o_local)][128 cols (node i)] bf16.
__device__ __forceinline__ int sw_idx(int o, int i) {
    return o * 128 + ((((i >> 3) ^ o) & 15) << 3) + (i & 7);
}

template<bool WSMASK>
__global__ __launch_bounds__(256, 3)
void gat_main_kernel(const float* __restrict__ hg, const float* __restrict__ adj,
                     const float* __restrict__ ag, const __bf16* __restrict__ Wt,
                     const unsigned* __restrict__ mws, float* __restrict__ out)
{
    const int bs  = blockIdx.x;
    const int tid = threadIdx.x;
    const int w   = tid >> 6;
    const int l   = tid & 63;
    const int l15 = l & 15;
    const int l4  = l >> 4;

    __shared__ __bf16   ht_t[128 * 128];                 // 32 KB (2 heads / pass)
    __shared__ float    src_sh[2][128], tgt_sh[2][128];  // 2 KB
    __shared__ unsigned mask_sh[WSMASK ? 4 : 512];

    const float* hb = hg + (size_t)bs * 128 * 64;

    // ---- mask bits -> registers (or LDS fallback) ----
    uint4 mq[2];
    if constexpr (WSMASK) {
        #pragma unroll
        for (int m2 = 0; m2 < 2; ++m2) {
            int irow = 16 * (2 * w + m2) + l15;
            mq[m2] = *reinterpret_cast<const uint4*>(mws + ((size_t)bs * 128 + irow) * 4);
        }
    } else {
        const float* ab = adj + (size_t)bs * 128 * 128;
        #pragma unroll
        for (int rp = 0; rp < 2; ++rp) {
            int widx = tid + rp * 256;
            int i = widx >> 2, wq = widx & 3;
            const float4* ap = reinterpret_cast<const float4*>(ab + i * 128 + wq * 32);
            unsigned bits = 0u;
            #pragma unroll
            for (int v = 0; v < 8; ++v) {
                float4 f = ap[v];
                bits |= (f.x < ADJ_TH ? 1u : 0u) << (4 * v + 0);
                bits |= (f.y < ADJ_TH ? 1u : 0u) << (4 * v + 1);
                bits |= (f.z < ADJ_TH ? 1u : 0u) << (4 * v + 2);
                bits |= (f.w < ADJ_TH ? 1u : 0u) << (4 * v + 3);
            }
            mask_sh[i * 4 + wq] = bits;
        }
    }

    // ---- A fragments of h, loaded ONCE (16 VGPRs, held) ----
    bf16x8 af[2][2];
    #pragma unroll
    for (int m2 = 0; m2 < 2; ++m2) {
        int row = 16 * (2 * w + m2) + l15;
        #pragma unroll
        for (int ks = 0; ks < 2; ++ks) {
            const float4* p4 = reinterpret_cast<const float4*>(hb + row * 64 + 8 * l4 + 32 * ks);
            float4 lo = p4[0], hi = p4[1];
            bf16x8 v;
            v[0]=(__bf16)lo.x; v[1]=(__bf16)lo.y; v[2]=(__bf16)lo.z; v[3]=(__bf16)lo.w;
            v[4]=(__bf16)hi.x; v[5]=(__bf16)hi.y; v[6]=(__bf16)hi.z; v[7]=(__bf16)hi.w;
            af[m2][ks] = v;
        }
    }

    f32x4 acc2[2][4];                   // GEMM2 accumulators (32 regs), persist
    #pragma unroll
    for (int m2 = 0; m2 < 2; ++m2)
        #pragma unroll
        for (int nt = 0; nt < 4; ++nt) { f32x4 z = {0.f,0.f,0.f,0.f}; acc2[m2][nt] = z; }

    #pragma unroll 1
    for (int p = 0; p < 2; ++p) {       // pass = head pair {2p, 2p+1}
        // ---- GEMM1 for this pass's 128 channels + fused src/tgt projections ----
        #pragma unroll 1
        for (int hg2 = 0; hg2 < 2; ++hg2) {
            int h = 2 * p + hg2;
            float ps[2][4], pt[2][4];
            #pragma unroll
            for (int m2 = 0; m2 < 2; ++m2)
                #pragma unroll
                for (int r = 0; r < 4; ++r) { ps[m2][r] = 0.f; pt[m2][r] = 0.f; }

            #pragma unroll
            for (int nq = 0; nq < 4; ++nq) {
                int nt   = 4 * hg2 + nq;
                int oloc = 16 * nt + l15;          // 0..127 within pass
                int og   = 128 * p + oloc;         // global channel
                int d    = 16 * nq + l15;          // channel within head
                float a_s = ag[h * 128 + d];
                float a_t = ag[h * 128 + 64 + d];
                bf16x8 b0 = *reinterpret_cast<const bf16x8*>(Wt + og * 64 + 8 * l4);
                bf16x8 b1 = *reinterpret_cast<const bf16x8*>(Wt + og * 64 + 8 * l4 + 32);
                #pragma unroll
                for (int m2 = 0; m2 < 2; ++m2) {
                    f32x4 acc = {0.f,0.f,0.f,0.f};
                    acc = __builtin_amdgcn_mfma_f32_16x16x32_bf16(af[m2][0], b0, acc, 0,0,0);
                    acc = __builtin_amdgcn_mfma_f32_16x16x32_bf16(af[m2][1], b1, acc, 0,0,0);
                    int i0 = 16 * (2 * w + m2) + 4 * l4;
                    bf16x4 st;
                    st[0]=(__bf16)acc[0]; st[1]=(__bf16)acc[1];
                    st[2]=(__bf16)acc[2]; st[3]=(__bf16)acc[3];
                    *reinterpret_cast<bf16x4*>(&ht_t[sw_idx(oloc, i0)]) = st;
                    #pragma unroll
                    for (int r = 0; r < 4; ++r) {
                        ps[m2][r] += acc[r] * a_s;
                        pt[m2][r] += acc[r] * a_t;
                    }
                }
            }
            #pragma unroll
            for (int s = 1; s < 16; s <<= 1)
                #pragma unroll
                for (int m2 = 0; m2 < 2; ++m2)
                    #pragma unroll
                    for (int r = 0; r < 4; ++r) {
                        ps[m2][r] += __shfl_xor(ps[m2][r], s);
                        pt[m2][r] += __shfl_xor(pt[m2][r], s);
                    }
            if (l15 == 0) {
                #pragma unroll
                for (int m2 = 0; m2 < 2; ++m2)
                    #pragma unroll
                    for (int r = 0; r < 4; ++r) {
                        int i = 16 * (2 * w + m2) + 4 * l4 + r;
                        src_sh[hg2][i] = ps[m2][r];
                        tgt_sh[hg2][i] = pt[m2][r];
                    }
            }
        }
        __syncthreads();

        // ---- phase 2: masked sigmoid-softmax + GEMM2 (B-frags streamed JIT) ----
        #pragma unroll 1
        for (int hp = 0; hp < 2; ++hp) {
            // P fragments for both row-tiles first (32 regs), then stream B.
            bf16x8 pa[2][4];
            #pragma unroll
            for (int m2 = 0; m2 < 2; ++m2) {
                int irow = 16 * (2 * w + m2) + l15;
                float si = src_sh[hp][irow];
                unsigned mw[4];
                if constexpr (WSMASK) {
                    mw[0]=mq[m2].x; mw[1]=mq[m2].y; mw[2]=mq[m2].z; mw[3]=mq[m2].w;
                } else {
                    uint4 t = *reinterpret_cast<const uint4*>(&mask_sh[irow * 4]);
                    mw[0]=t.x; mw[1]=t.y; mw[2]=t.z; mw[3]=t.w;
                }

                float pf[4][8];
                float dloc = 0.f;
                #pragma unroll
                for (int ks = 0; ks < 4; ++ks) {
                    const float4* tp = reinterpret_cast<const float4*>(&tgt_sh[hp][8 * l4 + 32 * ks]);
                    float4 t0 = tp[0], t1 = tp[1];
                    float tg[8] = {t0.x,t0.y,t0.z,t0.w,t1.x,t1.y,t1.z,t1.w};
                    #pragma unroll
                    for (int e = 0; e < 8; ++e) {
                        float x  = si + tg[e];
                        float sg = __builtin_amdgcn_rcpf(1.0f + __expf(-x));
                        float pe = __expf(sg);
                        float pv = ((mw[ks] >> (8 * l4 + e)) & 1u) ? 0.f : pe;
                        pf[ks][e] = pv;
                        dloc += pv;
                    }
                }
                dloc += __shfl_xor(dloc, 16);
                dloc += __shfl_xor(dloc, 32);
                float scale = 0.25f * __builtin_amdgcn_rcpf(fmaxf(dloc, 1e-20f));

                #pragma unroll
                for (int ks = 0; ks < 4; ++ks) {
                    bf16x8 v;
                    #pragma unroll
                    for (int e = 0; e < 8; ++e) v[e] = (__bf16)(pf[ks][e] * scale);
                    pa[m2][ks] = v;
                }
            }

            // GEMM2: stream B fragments from LDS, reuse each for both row-tiles.
            #pragma unroll
            for (int nt = 0; nt < 4; ++nt) {
                #pragma unroll
                for (int ks = 0; ks < 4; ++ks) {
                    bf16x8 b = *reinterpret_cast<const bf16x8*>(
                        &ht_t[sw_idx(64 * hp + 16 * nt + l15, 8 * l4 + 32 * ks)]);
                    acc2[0][nt] = __builtin_amdgcn_mfma_f32_16x16x32_bf16(pa[0][ks], b, acc2[0][nt], 0,0,0);
                    acc2[1][nt] = __builtin_amdgcn_mfma_f32_16x16x32_bf16(pa[1][ks], b, acc2[1][nt], 0,0,0);
                }
            }
        }
        __syncthreads();   // ht_t reused next pass
    }

    // ---- epilogue ----
    float* ob = out + (size_t)bs * 128 * 64;
    #pragma unroll
    for (int m2 = 0; m2 < 2; ++m2)
        #pragma unroll
        for (int nt = 0; nt < 4; ++nt)
            #pragma unroll
            for (int r = 0; r < 4; ++r)
                ob[(32 * w + 16 * m2 + 4 * l4 + r) * 64 + 16 * nt + l15] = acc2[m2][nt][r];
}

extern "C" void kernel_launch(void* const* d_in, const int* in_sizes, int n_in,
                              void* d_out, int out_size, void* d_ws, size_t ws_size,
                              hipStream_t stream) {
    const float* h   = (const float*)d_in[0];
    const float* adj = (const float*)d_in[1];
    const float* W   = (const float*)d_in[2];
    const float* a   = (const float*)d_in[3];
    float* out = (float*)d_out;

    __bf16*   Wt  = (__bf16*)d_ws;                              // 32 KB
    unsigned* mws = (unsigned*)((char*)d_ws + 65536);           // 1.25 MB
    const size_t need = 65536 + (size_t)640 * 128 * 4 * sizeof(unsigned);

    wt_convert_kernel<<<64, 256, 0, stream>>>(W, Wt);
    if (ws_size >= need) {
        mask_build_kernel<<<640, 256, 0, stream>>>(adj, mws);
        gat_main_kernel<true><<<640, 256, 0, stream>>>(h, adj, a, Wt, mws, out);
    } else {
        gat_main_kernel<false><<<640, 256, 0, stream>>>(h, adj, a, Wt, mws, out);
    }
}